// Round 4
// baseline (522.706 us; speedup 1.0000x reference)
//
#include <hip/hip_runtime.h>

#define B_ 2
#define S_ 2048
#define L_ 2048
#define H_ 16
#define KVH_ 4
#define D_ 128
#define HID_ 2048
#define EPS_ 1e-6f

typedef unsigned short u16;
typedef unsigned int u32;
typedef __bf16 bf16x8 __attribute__((ext_vector_type(8)));
typedef float f32x4 __attribute__((ext_vector_type(4)));
typedef unsigned u32x2v __attribute__((ext_vector_type(2)));
typedef unsigned u32x4v __attribute__((ext_vector_type(4)));

__device__ __forceinline__ float bf2f(u32 u) {
  union { u32 i; float f; } x; x.i = u << 16; return x.f;
}
__device__ __forceinline__ u16 f2bf(float f) {
  union { float f; u32 i; } x; x.f = f;
  return (u16)((x.i + 0x7fffu + ((x.i >> 16) & 1u)) >> 16);
}
__device__ __forceinline__ u32 pack_bf16(float a, float b) {
#if __has_builtin(__builtin_amdgcn_cvt_pk_bf16_f32)
  typedef __bf16 bf16x2 __attribute__((ext_vector_type(2)));
  union { bf16x2 v; u32 u; } c;
  c.v = __builtin_amdgcn_cvt_pk_bf16_f32(a, b);
  return c.u;
#else
  return (u32)f2bf(a) | ((u32)f2bf(b) << 16);
#endif
}
__device__ __forceinline__ float fexp2(float x) {
#if __has_builtin(__builtin_amdgcn_exp2f)
  return __builtin_amdgcn_exp2f(x);  // single v_exp_f32; softmax tolerates FTZ
#else
  return exp2f(x);
#endif
}
// async global->LDS, 16B per lane. LDS dest = wave-uniform base + lane*16.
__device__ __forceinline__ void gl2lds16(const u16* g, u16* l) {
  __builtin_amdgcn_global_load_lds(
      (const __attribute__((address_space(1))) u32*)g,
      (__attribute__((address_space(3))) u32*)l, 16, 0, 0);
}

#if __has_builtin(__builtin_amdgcn_permlane32_swap) && __has_builtin(__builtin_amdgcn_permlane16_swap)
#define HAS_PLS 1
#else
#define HAS_PLS 0
#endif

// MFMA C-layout (2 16x16 tiles, packed bf16 pairs) -> one K=32 A-frag.
__device__ __forceinline__ u32x4v ctoa(u32 xa, u32 xb, u32 ya, u32 yb,
                                       int quad, int l15) {
  u32x4v f;
#if HAS_PLS
  u32x2v t1 = __builtin_amdgcn_permlane32_swap(xa, ya, false, false);
  u32x2v t2 = __builtin_amdgcn_permlane16_swap(t1.x, t1.y, false, false);
  u32x2v t3 = __builtin_amdgcn_permlane32_swap(xb, yb, false, false);
  u32x2v t4 = __builtin_amdgcn_permlane16_swap(t3.x, t3.y, false, false);
  f.x = t2.x; f.y = t4.x; f.z = t2.y; f.w = t4.y;
#else
  int a0 = (((2 * quad) & 3) * 16 + l15) << 2;
  int a1 = (((2 * quad + 1) & 3) * 16 + l15) << 2;
  u32 xa0 = __builtin_amdgcn_ds_bpermute(a0, xa), ya0 = __builtin_amdgcn_ds_bpermute(a0, ya);
  u32 xb0 = __builtin_amdgcn_ds_bpermute(a0, xb), yb0 = __builtin_amdgcn_ds_bpermute(a0, yb);
  u32 xa1 = __builtin_amdgcn_ds_bpermute(a1, xa), ya1 = __builtin_amdgcn_ds_bpermute(a1, ya);
  u32 xb1 = __builtin_amdgcn_ds_bpermute(a1, xb), yb1 = __builtin_amdgcn_ds_bpermute(a1, yb);
  bool hi = quad >= 2;
  f.x = hi ? ya0 : xa0; f.y = hi ? yb0 : xb0;
  f.z = hi ? ya1 : xa1; f.w = hi ? yb1 : xb1;
#endif
  return f;
}

// ---------------- elementwise fp32 -> bf16 cast ----------------
__global__ __launch_bounds__(256) void cvt_bf16(const float* __restrict__ in,
                                                u16* __restrict__ out, int n4) {
  int i = blockIdx.x * 256 + threadIdx.x;
  if (i >= n4) return;
  float4 v = ((const float4*)in)[i];
  uint2 o;
  o.x = pack_bf16(v.x, v.y);
  o.y = pack_bf16(v.z, v.w);
  ((uint2*)out)[i] = o;
}

// ---------------- LDS-tiled transpose fp32[R][C] -> bf16[C][R] ----------------
__global__ __launch_bounds__(256) void transp_bf16(const float* __restrict__ A,
                                                   u16* __restrict__ At, int R, int C) {
  __shared__ float t[64][65];
  int c0 = blockIdx.x * 64, r0 = blockIdx.y * 64;
  int tx = threadIdx.x & 63, ty = threadIdx.x >> 6;
  for (int i = ty; i < 64; i += 4)
    t[i][tx] = A[(size_t)(r0 + i) * C + c0 + tx];
  __syncthreads();
  for (int i = ty; i < 64; i += 4)
    At[(size_t)(c0 + i) * R + r0 + tx] = f2bf(t[tx][i]);
}

// ---------------- bf16 GEMM: C[M][N] = A[M][K] @ Bt[N][K]^T ----------------
__device__ __forceinline__ void store_out(u16* p, float v) { *p = f2bf(v); }
__device__ __forceinline__ void store_out(float* p, float v) { *p = v; }

template <typename OutT>
__global__ __launch_bounds__(256, 2) void gemm_bt(const u16* __restrict__ A,
                                                  const u16* __restrict__ Bt,
                                                  OutT* __restrict__ C,
                                                  int M, int N, int K) {
  __shared__ u16 sA[128 * 32];
  __shared__ u16 sB[128 * 32];
  const int tid = threadIdx.x;
  const int wave = tid >> 6, lane = tid & 63;
  const int quad = lane >> 4, l15 = lane & 15;
  const int m0 = blockIdx.x * 128, n0 = blockIdx.y * 128;
  const int wm = (wave >> 1) * 64, wn = (wave & 1) * 64;
  const u16* aP = A + (size_t)m0 * K;
  const u16* bP = Bt + (size_t)n0 * K;
  const int sr = lane >> 2;
  const int sc = (lane & 3) * 8;
  const int r0 = wave * 32, r1 = wave * 32 + 16;

  f32x4 acc[4][4];
  for (int i = 0; i < 4; i++)
    for (int j = 0; j < 4; j++)
      for (int r = 0; r < 4; r++) acc[i][j][r] = 0.0f;

  for (int k0 = 0; k0 < K; k0 += 32) {
    gl2lds16(aP + (size_t)(r0 + sr) * K + k0 + sc, &sA[r0 * 32]);
    gl2lds16(aP + (size_t)(r1 + sr) * K + k0 + sc, &sA[r1 * 32]);
    gl2lds16(bP + (size_t)(r0 + sr) * K + k0 + sc, &sB[r0 * 32]);
    gl2lds16(bP + (size_t)(r1 + sr) * K + k0 + sc, &sB[r1 * 32]);
    __syncthreads();
    bf16x8 afrag[4], bfrag[4];
    for (int i = 0; i < 4; i++)
      afrag[i] = *(const bf16x8*)&sA[(wm + i * 16 + l15) * 32 + quad * 8];
    for (int j = 0; j < 4; j++)
      bfrag[j] = *(const bf16x8*)&sB[(wn + j * 16 + l15) * 32 + quad * 8];
    for (int i = 0; i < 4; i++)
      for (int j = 0; j < 4; j++)
        acc[i][j] = __builtin_amdgcn_mfma_f32_16x16x32_bf16(afrag[i], bfrag[j], acc[i][j], 0, 0, 0);
    __syncthreads();
  }
  for (int i = 0; i < 4; i++)
    for (int j = 0; j < 4; j++) {
      int row = m0 + wm + i * 16 + quad * 4;
      int col = n0 + wn + j * 16 + l15;
      for (int r = 0; r < 4; r++)
        store_out(&C[(size_t)(row + r) * N + col], acc[i][j][r]);
    }
}

// ---------------- K-norm + deinterleave CKV -> K, V^T (coalesced) ----------------
__global__ __launch_bounds__(256) void knorm_deint(const u16* __restrict__ CKV,
                                                   const float* __restrict__ w,
                                                   u16* __restrict__ K,
                                                   u16* __restrict__ Vt) {
  __shared__ u16 vbuf[128][66];
  const int tid = threadIdx.x, wave = tid >> 6, lane = tid & 63;
  const int l0 = blockIdx.x * 64, kvh = blockIdx.y, b = blockIdx.z;
  for (int it = 0; it < 16; it++) {
    int ll = wave * 16 + it;
    int row = b * L_ + l0 + ll;
    const u16* src = CKV + (size_t)row * 1024 + kvh * 256;
    u32 p0 = *(const u32*)&src[lane * 2];
    u32 p1 = *(const u32*)&src[(lane + 64) * 2];
    float k0 = bf2f(p0 & 0xffff), v0 = bf2f(p0 >> 16);
    float k1 = bf2f(p1 & 0xffff), v1 = bf2f(p1 >> 16);
    float ss = k0 * k0 + k1 * k1;
    for (int off = 1; off < 64; off <<= 1) ss += __shfl_xor(ss, off);
    float sc = rsqrtf(ss * (1.0f / 128.0f) + EPS_);
    size_t kb = (((size_t)b * KVH_ + kvh) * L_ + l0 + ll) * D_;
    K[kb + lane] = f2bf(k0 * sc * w[lane]);
    K[kb + lane + 64] = f2bf(k1 * sc * w[lane + 64]);
    vbuf[lane][ll] = f2bf(v0);
    vbuf[lane + 64][ll] = f2bf(v1);
  }
  __syncthreads();
  for (int it = tid; it < 128 * 32; it += 256) {
    int d = it >> 5, cc = (it & 31) * 2;
    u32 pk = (u32)vbuf[d][cc] | ((u32)vbuf[d][cc + 1] << 16);
    *(u32*)&Vt[(((size_t)b * KVH_ + kvh) * D_ + d) * L_ + l0 + cc] = pk;
  }
}

// ---------------- flash attention ----------------
// 8 waves x (32 q-rows x 32-l half): wave (qsub, lh) computes q-rows
// qsub*32..+32 against l-half lh of each 64-l KV tile. This restores 2x
// fragment reuse (every kf/vf LDS read feeds 2 MFMAs => 0.5 KB/MFMA) at
// 4 waves/SIMD occupancy -- R3 was LDS-read-bound at 93% of the b128
// throughput ceiling. O/psum partials over l are cross-wave reduced once
// in the epilogue via LDS aliased over the dead staging buffers.
// KV-tile 64 double-buffered, counted-vmcnt raw barriers, XOR-swizzle.
__global__ __launch_bounds__(512, 4) void attn(const u16* __restrict__ XQ,
                                               const float* __restrict__ nw,
                                               const u16* __restrict__ K,
                                               const u16* __restrict__ Vt,
                                               u16* __restrict__ AO) {
  __shared__ union __align__(16) SMem {
    struct { u16 sk[2][4][64 * 32]; u16 sv[2][2][128 * 32]; } s;  // 64KB staging
    struct { float ob[4][32][132]; float ps[4][32]; } e;          // epilogue reduce
  } sm;
  const int tid = threadIdx.x, wave = tid >> 6, lane = tid & 63;
  const int quad = lane >> 4, l15 = lane & 15;
  const int qt = blockIdx.x, h = blockIdx.y, b = blockIdx.z;
  const int kvh = h >> 2;
  const int qsub = wave & 3, lh = wave >> 2;
  const int s0 = qt * 128, wr0 = qsub * 32;

  const u16* kbase = K + ((size_t)(b * KVH_ + kvh) * L_) * D_;
  const u16* vbase = Vt + ((size_t)(b * KVH_ + kvh) * D_) * L_;
  // Staging: LDS dest linear (row = lane>>2, slot = lane&3); global source
  // slot XOR'd with (row>>1)&3 == (lane>>3)&3. Involution, coalescing kept.
  const int srow = lane >> 2;
  const int scol = ((lane & 3) ^ ((lane >> 3) & 3)) * 8;
  const int swq = (quad ^ ((l15 >> 1) & 3)) * 8;  // read-side XOR
  // stage roles: 8 waves x (2 K-loads + 2 V-loads)
  const int kch = wave >> 1, khalf = wave & 1;   // K: d-chunk, row-half
  const int vch = wave >> 2, vqtr = wave & 3;    // V: l-chunk, d-quarter

  // Stage one 64-l KV tile into buffer `buf` (4 gl2lds16 per wave).
  auto stage = [&](int l0, int buf) {
    const u16* kb = kbase + (size_t)l0 * D_ + kch * 32;
    for (int is = 0; is < 2; is++) {
      int row = khalf * 32 + is * 16;
      gl2lds16(kb + (size_t)(row + srow) * D_ + scol, &sm.s.sk[buf][kch][row * 32]);
    }
    const u16* vb = vbase + l0 + vch * 32;
    for (int is = 0; is < 2; is++) {
      int drow = vqtr * 32 + is * 16;
      gl2lds16(vb + (size_t)(drow + srow) * L_ + scol, &sm.s.sv[buf][vch][drow * 32]);
    }
  };

  // ---- one-time: load 32 q-rows, fused RMSNorm (+SCALE*log2e), to A-frags ----
  bf16x8 qf[2][4];
  {
    const float cexp = 0.12753102331322172f;  // (1/sqrt(128)) * log2(e)
    const u16* qrow = XQ + (size_t)(b * S_ + s0 + wr0 + l15) * HID_ + h * D_;
    for (int i = 0; i < 2; i++) {
      const u16* qr = qrow + (size_t)i * 16 * HID_;
      float vals[4][8];
      float ss = 0.0f;
      for (int kc = 0; kc < 4; kc++) {
        uint4 u = *(const uint4*)&qr[kc * 32 + quad * 8];
        u32 uu[4] = {u.x, u.y, u.z, u.w};
        for (int e = 0; e < 4; e++) {
          float lo = bf2f(uu[e] & 0xffff), hi = bf2f(uu[e] >> 16);
          vals[kc][2 * e] = lo;
          vals[kc][2 * e + 1] = hi;
          ss += lo * lo + hi * hi;
        }
      }
      ss += __shfl_xor(ss, 16);
      ss += __shfl_xor(ss, 32);
      float scale = rsqrtf(ss * (1.0f / 128.0f) + EPS_) * cexp;
      for (int kc = 0; kc < 4; kc++) {
        float4 w0 = *(const float4*)&nw[kc * 32 + quad * 8];
        float4 w1 = *(const float4*)&nw[kc * 32 + quad * 8 + 4];
        union { u32x4v u; bf16x8 v; } q;
        q.u.x = pack_bf16(vals[kc][0] * scale * w0.x, vals[kc][1] * scale * w0.y);
        q.u.y = pack_bf16(vals[kc][2] * scale * w0.z, vals[kc][3] * scale * w0.w);
        q.u.z = pack_bf16(vals[kc][4] * scale * w1.x, vals[kc][5] * scale * w1.y);
        q.u.w = pack_bf16(vals[kc][6] * scale * w1.z, vals[kc][7] * scale * w1.w);
        qf[i][kc] = q.v;
      }
    }
  }

  float psum[2] = {0.0f, 0.0f};
  f32x4 o[2][8];
  for (int i = 0; i < 2; i++)
    for (int n = 0; n < 8; n++)
      for (int r = 0; r < 4; r++) o[i][n][r] = 0.0f;

  stage(0, 0);
  int cur = 0;
  const int NT = L_ / 64;  // 32
  for (int t = 0; t < NT; t++) {
    if (t + 1 < NT) {
      stage((t + 1) * 64, cur ^ 1);
      // tile t's 4 oldest loads (per wave) must land; t+1's 4 stay in flight.
      asm volatile("s_waitcnt vmcnt(4)\n\ts_barrier" ::: "memory");
    } else {
      asm volatile("s_waitcnt vmcnt(0)\n\ts_barrier" ::: "memory");
    }

    // this wave's 32-l half of the tile
    {
      f32x4 sacc[2][2];
      for (int jj = 0; jj < 2; jj++)
        for (int i = 0; i < 2; i++)
          for (int r = 0; r < 4; r++) sacc[jj][i][r] = 0.0f;
      __builtin_amdgcn_s_setprio(1);
      for (int jj = 0; jj < 2; jj++) {
        int j = lh * 2 + jj;
        for (int kc = 0; kc < 4; kc++) {
          bf16x8 kf = *(const bf16x8*)&sm.s.sk[cur][kc][(j * 16 + l15) * 32 + swq];
          for (int i = 0; i < 2; i++)
            sacc[jj][i] = __builtin_amdgcn_mfma_f32_16x16x32_bf16(kf, qf[i][kc], sacc[jj][i], 0, 0, 0);
        }
      }
      __builtin_amdgcn_s_setprio(0);
      // p = exp2(s); per-lane partial row sums; pack + C->A in registers
      union { u32x4v u; bf16x8 v; } pf[2];
      for (int i = 0; i < 2; i++) {
        float p0[4], p1[4];
        for (int r = 0; r < 4; r++) {
          p0[r] = fexp2(sacc[0][i][r]);
          p1[r] = fexp2(sacc[1][i][r]);
          psum[i] += p0[r] + p1[r];
        }
        u32 xa = pack_bf16(p0[0], p0[1]), xb = pack_bf16(p0[2], p0[3]);
        u32 ya = pack_bf16(p1[0], p1[1]), yb = pack_bf16(p1[2], p1[3]);
        pf[i].u = ctoa(xa, xb, ya, yb, quad, l15);
      }
      // O += P V for this wave's 32-l chunk
      __builtin_amdgcn_s_setprio(1);
      for (int n = 0; n < 8; n++) {
        bf16x8 vf = *(const bf16x8*)&sm.s.sv[cur][lh][(n * 16 + l15) * 32 + swq];
        for (int i = 0; i < 2; i++)
          o[i][n] = __builtin_amdgcn_mfma_f32_16x16x32_bf16(pf[i].v, vf, o[i][n], 0, 0, 0);
      }
      __builtin_amdgcn_s_setprio(0);
    }
    // all waves done reading buf[cur] before it is restaged next iteration
    asm volatile("s_barrier" ::: "memory");
    cur ^= 1;
  }

  // ---- epilogue: cross-wave (lh) reduce of O and psum, then scale+store ----
  // quad-reduce psum: value valid for q-row = i*16 + l15, replicated per quad
  float sred[2];
  for (int i = 0; i < 2; i++) {
    float s = psum[i];
    s += __shfl_xor(s, 16);
    s += __shfl_xor(s, 32);
    sred[i] = s;
  }
  if (lh == 1) {
    for (int i = 0; i < 2; i++)
      for (int n = 0; n < 8; n++)
        for (int r = 0; r < 4; r++)
          sm.e.ob[qsub][i * 16 + quad * 4 + r][n * 16 + l15] = o[i][n][r];
    if (quad == 0)
      for (int i = 0; i < 2; i++) sm.e.ps[qsub][i * 16 + l15] = sred[i];
  }
  __syncthreads();
  if (lh == 0) {
    for (int i = 0; i < 2; i++) {
      float stot = sred[i] + sm.e.ps[qsub][i * 16 + l15];
      float linv = 1.0f / stot;
      float lr[4];
      for (int r = 0; r < 4; r++) lr[r] = __shfl(linv, quad * 4 + r);
      u16* ob = AO + (size_t)(b * S_ + s0 + wr0 + i * 16) * HID_ + h * D_;
      for (int n = 0; n < 8; n++)
        for (int r = 0; r < 4; r++) {
          float v = o[i][n][r] + sm.e.ob[qsub][i * 16 + quad * 4 + r][n * 16 + l15];
          ob[(size_t)(quad * 4 + r) * HID_ + n * 16 + l15] = f2bf(v * lr[r]);
        }
    }
  }
}

// ---------------- launch ----------------
extern "C" void kernel_launch(void* const* d_in, const int* in_sizes, int n_in,
                              void* d_out, int out_size, void* d_ws, size_t ws_size,
                              hipStream_t stream) {
  const float* x = (const float*)d_in[0];
  const float* c = (const float*)d_in[1];
  const float* wq = (const float*)d_in[2];
  const float* wkv = (const float*)d_in[3];
  const float* wo = (const float*)d_in[4];
  const float* nqw = (const float*)d_in[5];
  const float* nkw = (const float*)d_in[6];
  float* out = (float*)d_out;

  const int M = B_ * S_;  // 4096
  char* p = (char*)d_ws;
  auto alloc = [&](size_t bytes) {
    char* r = p;
    p += (bytes + 255) & ~(size_t)255;
    return r;
  };
  u16* xbf = (u16*)alloc((size_t)M * HID_ * 2);
  u16* cbf = (u16*)alloc((size_t)M * HID_ * 2);
  u16* wqT = (u16*)alloc((size_t)HID_ * HID_ * 2);
  u16* wkvT = (u16*)alloc((size_t)1024 * HID_ * 2);
  u16* woT = (u16*)alloc((size_t)HID_ * HID_ * 2);
  u16* XQ = (u16*)alloc((size_t)M * HID_ * 2);
  u16* CKV = (u16*)alloc((size_t)M * 1024 * 2);
  u16* Kb = (u16*)alloc((size_t)B_ * KVH_ * L_ * D_ * 2);
  u16* Vt = (u16*)alloc((size_t)B_ * KVH_ * D_ * L_ * 2);
  u16* AO = (u16*)alloc((size_t)M * HID_ * 2);

  cvt_bf16<<<8192, 256, 0, stream>>>(x, xbf, M * HID_ / 4);
  cvt_bf16<<<8192, 256, 0, stream>>>(c, cbf, M * HID_ / 4);
  transp_bf16<<<dim3(32, 32), 256, 0, stream>>>(wq, wqT, HID_, HID_);
  transp_bf16<<<dim3(16, 32), 256, 0, stream>>>(wkv, wkvT, HID_, 1024);
  transp_bf16<<<dim3(32, 32), 256, 0, stream>>>(wo, woT, HID_, HID_);
  gemm_bt<u16><<<dim3(32, 16), 256, 0, stream>>>(xbf, wqT, XQ, M, HID_, HID_);
  gemm_bt<u16><<<dim3(32, 8), 256, 0, stream>>>(cbf, wkvT, CKV, M, 1024, HID_);
  knorm_deint<<<dim3(32, 4, 2), 256, 0, stream>>>(CKV, nkw, Kb, Vt);
  attn<<<dim3(16, 16, 2), 512, 0, stream>>>(XQ, nqw, Kb, Vt, AO);
  gemm_bt<float><<<dim3(32, 16), 256, 0, stream>>>(AO, woT, out, M, HID_, HID_);
}

// Round 5
// 403.388 us; speedup vs baseline: 1.2958x; 1.2958x over previous
//
#include <hip/hip_runtime.h>

#define B_ 2
#define S_ 2048
#define L_ 2048
#define H_ 16
#define KVH_ 4
#define D_ 128
#define HID_ 2048
#define EPS_ 1e-6f

typedef unsigned short u16;
typedef unsigned int u32;
typedef __bf16 bf16x8 __attribute__((ext_vector_type(8)));
typedef float f32x4 __attribute__((ext_vector_type(4)));
typedef unsigned u32x2v __attribute__((ext_vector_type(2)));
typedef unsigned u32x4v __attribute__((ext_vector_type(4)));

__device__ __forceinline__ float bf2f(u32 u) {
  union { u32 i; float f; } x; x.i = u << 16; return x.f;
}
__device__ __forceinline__ u16 f2bf(float f) {
  union { float f; u32 i; } x; x.f = f;
  return (u16)((x.i + 0x7fffu + ((x.i >> 16) & 1u)) >> 16);
}
__device__ __forceinline__ u32 pack_bf16(float a, float b) {
#if __has_builtin(__builtin_amdgcn_cvt_pk_bf16_f32)
  typedef __bf16 bf16x2 __attribute__((ext_vector_type(2)));
  union { bf16x2 v; u32 u; } c;
  c.v = __builtin_amdgcn_cvt_pk_bf16_f32(a, b);
  return c.u;
#else
  return (u32)f2bf(a) | ((u32)f2bf(b) << 16);
#endif
}
__device__ __forceinline__ float fexp2(float x) {
#if __has_builtin(__builtin_amdgcn_exp2f)
  return __builtin_amdgcn_exp2f(x);  // single v_exp_f32; softmax tolerates FTZ
#else
  return exp2f(x);
#endif
}
// async global->LDS, 16B per lane. LDS dest = wave-uniform base + lane*16.
__device__ __forceinline__ void gl2lds16(const u16* g, u16* l) {
  __builtin_amdgcn_global_load_lds(
      (const __attribute__((address_space(1))) u32*)g,
      (__attribute__((address_space(3))) u32*)l, 16, 0, 0);
}

#if __has_builtin(__builtin_amdgcn_permlane32_swap) && __has_builtin(__builtin_amdgcn_permlane16_swap)
#define HAS_PLS 1
#else
#define HAS_PLS 0
#endif

// MFMA C-layout (2 16x16 tiles, packed bf16 pairs) -> one K=32 A-frag.
__device__ __forceinline__ u32x4v ctoa(u32 xa, u32 xb, u32 ya, u32 yb,
                                       int quad, int l15) {
  u32x4v f;
#if HAS_PLS
  u32x2v t1 = __builtin_amdgcn_permlane32_swap(xa, ya, false, false);
  u32x2v t2 = __builtin_amdgcn_permlane16_swap(t1.x, t1.y, false, false);
  u32x2v t3 = __builtin_amdgcn_permlane32_swap(xb, yb, false, false);
  u32x2v t4 = __builtin_amdgcn_permlane16_swap(t3.x, t3.y, false, false);
  f.x = t2.x; f.y = t4.x; f.z = t2.y; f.w = t4.y;
#else
  int a0 = (((2 * quad) & 3) * 16 + l15) << 2;
  int a1 = (((2 * quad + 1) & 3) * 16 + l15) << 2;
  u32 xa0 = __builtin_amdgcn_ds_bpermute(a0, xa), ya0 = __builtin_amdgcn_ds_bpermute(a0, ya);
  u32 xb0 = __builtin_amdgcn_ds_bpermute(a0, xb), yb0 = __builtin_amdgcn_ds_bpermute(a0, yb);
  u32 xa1 = __builtin_amdgcn_ds_bpermute(a1, xa), ya1 = __builtin_amdgcn_ds_bpermute(a1, ya);
  u32 xb1 = __builtin_amdgcn_ds_bpermute(a1, xb), yb1 = __builtin_amdgcn_ds_bpermute(a1, yb);
  bool hi = quad >= 2;
  f.x = hi ? ya0 : xa0; f.y = hi ? yb0 : xb0;
  f.z = hi ? ya1 : xa1; f.w = hi ? yb1 : xb1;
#endif
  return f;
}

// ---------------- elementwise fp32 -> bf16 cast ----------------
__global__ __launch_bounds__(256) void cvt_bf16(const float* __restrict__ in,
                                                u16* __restrict__ out, int n4) {
  int i = blockIdx.x * 256 + threadIdx.x;
  if (i >= n4) return;
  float4 v = ((const float4*)in)[i];
  uint2 o;
  o.x = pack_bf16(v.x, v.y);
  o.y = pack_bf16(v.z, v.w);
  ((uint2*)out)[i] = o;
}

// ---------------- LDS-tiled transpose fp32[R][C] -> bf16[C][R] ----------------
__global__ __launch_bounds__(256) void transp_bf16(const float* __restrict__ A,
                                                   u16* __restrict__ At, int R, int C) {
  __shared__ float t[64][65];
  int c0 = blockIdx.x * 64, r0 = blockIdx.y * 64;
  int tx = threadIdx.x & 63, ty = threadIdx.x >> 6;
  for (int i = ty; i < 64; i += 4)
    t[i][tx] = A[(size_t)(r0 + i) * C + c0 + tx];
  __syncthreads();
  for (int i = ty; i < 64; i += 4)
    At[(size_t)(c0 + i) * R + r0 + tx] = f2bf(t[tx][i]);
}

// ---------------- bf16 GEMM: C[M][N] = A[M][K] @ Bt[N][K]^T ----------------
__device__ __forceinline__ void store_out(u16* p, float v) { *p = f2bf(v); }
__device__ __forceinline__ void store_out(float* p, float v) { *p = v; }

template <typename OutT>
__global__ __launch_bounds__(256, 2) void gemm_bt(const u16* __restrict__ A,
                                                  const u16* __restrict__ Bt,
                                                  OutT* __restrict__ C,
                                                  int M, int N, int K) {
  __shared__ u16 sA[128 * 32];
  __shared__ u16 sB[128 * 32];
  const int tid = threadIdx.x;
  const int wave = tid >> 6, lane = tid & 63;
  const int quad = lane >> 4, l15 = lane & 15;
  const int m0 = blockIdx.x * 128, n0 = blockIdx.y * 128;
  const int wm = (wave >> 1) * 64, wn = (wave & 1) * 64;
  const u16* aP = A + (size_t)m0 * K;
  const u16* bP = Bt + (size_t)n0 * K;
  const int sr = lane >> 2;
  const int sc = (lane & 3) * 8;
  const int r0 = wave * 32, r1 = wave * 32 + 16;

  f32x4 acc[4][4];
  for (int i = 0; i < 4; i++)
    for (int j = 0; j < 4; j++)
      for (int r = 0; r < 4; r++) acc[i][j][r] = 0.0f;

  for (int k0 = 0; k0 < K; k0 += 32) {
    gl2lds16(aP + (size_t)(r0 + sr) * K + k0 + sc, &sA[r0 * 32]);
    gl2lds16(aP + (size_t)(r1 + sr) * K + k0 + sc, &sA[r1 * 32]);
    gl2lds16(bP + (size_t)(r0 + sr) * K + k0 + sc, &sB[r0 * 32]);
    gl2lds16(bP + (size_t)(r1 + sr) * K + k0 + sc, &sB[r1 * 32]);
    __syncthreads();
    bf16x8 afrag[4], bfrag[4];
    for (int i = 0; i < 4; i++)
      afrag[i] = *(const bf16x8*)&sA[(wm + i * 16 + l15) * 32 + quad * 8];
    for (int j = 0; j < 4; j++)
      bfrag[j] = *(const bf16x8*)&sB[(wn + j * 16 + l15) * 32 + quad * 8];
    for (int i = 0; i < 4; i++)
      for (int j = 0; j < 4; j++)
        acc[i][j] = __builtin_amdgcn_mfma_f32_16x16x32_bf16(afrag[i], bfrag[j], acc[i][j], 0, 0, 0);
    __syncthreads();
  }
  for (int i = 0; i < 4; i++)
    for (int j = 0; j < 4; j++) {
      int row = m0 + wm + i * 16 + quad * 4;
      int col = n0 + wn + j * 16 + l15;
      for (int r = 0; r < 4; r++)
        store_out(&C[(size_t)(row + r) * N + col], acc[i][j][r]);
    }
}

// ---------------- K-norm + deinterleave CKV -> K, V^T (coalesced) ----------------
__global__ __launch_bounds__(256) void knorm_deint(const u16* __restrict__ CKV,
                                                   const float* __restrict__ w,
                                                   u16* __restrict__ K,
                                                   u16* __restrict__ Vt) {
  __shared__ u16 vbuf[128][66];
  const int tid = threadIdx.x, wave = tid >> 6, lane = tid & 63;
  const int l0 = blockIdx.x * 64, kvh = blockIdx.y, b = blockIdx.z;
  for (int it = 0; it < 16; it++) {
    int ll = wave * 16 + it;
    int row = b * L_ + l0 + ll;
    const u16* src = CKV + (size_t)row * 1024 + kvh * 256;
    u32 p0 = *(const u32*)&src[lane * 2];
    u32 p1 = *(const u32*)&src[(lane + 64) * 2];
    float k0 = bf2f(p0 & 0xffff), v0 = bf2f(p0 >> 16);
    float k1 = bf2f(p1 & 0xffff), v1 = bf2f(p1 >> 16);
    float ss = k0 * k0 + k1 * k1;
    for (int off = 1; off < 64; off <<= 1) ss += __shfl_xor(ss, off);
    float sc = rsqrtf(ss * (1.0f / 128.0f) + EPS_);
    size_t kb = (((size_t)b * KVH_ + kvh) * L_ + l0 + ll) * D_;
    K[kb + lane] = f2bf(k0 * sc * w[lane]);
    K[kb + lane + 64] = f2bf(k1 * sc * w[lane + 64]);
    vbuf[lane][ll] = f2bf(v0);
    vbuf[lane + 64][ll] = f2bf(v1);
  }
  __syncthreads();
  for (int it = tid; it < 128 * 32; it += 256) {
    int d = it >> 5, cc = (it & 31) * 2;
    u32 pk = (u32)vbuf[d][cc] | ((u32)vbuf[d][cc + 1] << 16);
    *(u32*)&Vt[(((size_t)b * KVH_ + kvh) * D_ + d) * L_ + l0 + cc] = pk;
  }
}

// ---------------- flash attention ----------------
// 8 waves = 4 q-subtiles (16 rows each, R3's proven 52-VGPR footprint) x
// 2 l-halves (split-L: each wave reads only HALF the 64-l KV tile => per-CU
// LDS read traffic halves vs R3, which ran at ~95% of the ds_read_b128 pipe
// ceiling). q=32/wave at 4 waves/SIMD is infeasible (R4: 128-reg cap ->
// spill, 430MB scratch); q=16 fits with ~40 regs of headroom.
// Cross-lh O/psum reduction once in the epilogue via LDS aliased over the
// dead staging buffers. KV-tile 64 double-buffered, counted-vmcnt barriers,
// XOR-swizzle, setprio.
__global__ __launch_bounds__(512, 4) void attn(const u16* __restrict__ XQ,
                                               const float* __restrict__ nw,
                                               const u16* __restrict__ K,
                                               const u16* __restrict__ Vt,
                                               u16* __restrict__ AO) {
  __shared__ union __align__(16) SMem {
    struct { u16 sk[2][4][64 * 32]; u16 sv[2][2][128 * 32]; } s;  // 64KB staging
    struct { float ob[4][16][132]; float ps[4][16]; } e;          // epilogue reduce
  } sm;
  const int tid = threadIdx.x, wave = tid >> 6, lane = tid & 63;
  const int quad = lane >> 4, l15 = lane & 15;
  const int qt = blockIdx.x, h = blockIdx.y, b = blockIdx.z;
  const int kvh = h >> 2;
  const int qsub = wave & 3, lh = wave >> 2;
  const int s0 = qt * 64, wr0 = qsub * 16;

  const u16* kbase = K + ((size_t)(b * KVH_ + kvh) * L_) * D_;
  const u16* vbase = Vt + ((size_t)(b * KVH_ + kvh) * D_) * L_;
  // Staging: LDS dest linear (row = lane>>2, slot = lane&3); global source
  // slot XOR'd with (row>>1)&3 == (lane>>3)&3. Involution, coalescing kept.
  const int srow = lane >> 2;
  const int scol = ((lane & 3) ^ ((lane >> 3) & 3)) * 8;
  const int swq = (quad ^ ((l15 >> 1) & 3)) * 8;  // read-side XOR
  // stage roles: 8 waves x (2 K-loads + 2 V-loads)
  const int kch = wave >> 1, khalf = wave & 1;   // K: d-chunk, row-half
  const int vch = wave >> 2, vqtr = wave & 3;    // V: l-chunk, d-quarter

  // Stage one 64-l KV tile into buffer `buf` (4 gl2lds16 per wave).
  auto stage = [&](int l0, int buf) {
    const u16* kb = kbase + (size_t)l0 * D_ + kch * 32;
    for (int is = 0; is < 2; is++) {
      int row = khalf * 32 + is * 16;
      gl2lds16(kb + (size_t)(row + srow) * D_ + scol, &sm.s.sk[buf][kch][row * 32]);
    }
    const u16* vb = vbase + l0 + vch * 32;
    for (int is = 0; is < 2; is++) {
      int drow = vqtr * 32 + is * 16;
      gl2lds16(vb + (size_t)(drow + srow) * L_ + scol, &sm.s.sv[buf][vch][drow * 32]);
    }
  };

  // ---- one-time: load 16 q-rows, fused RMSNorm (+SCALE*log2e), to A-frags ----
  bf16x8 qf[4];
  {
    const float cexp = 0.12753102331322172f;  // (1/sqrt(128)) * log2(e)
    const u16* qr = XQ + (size_t)(b * S_ + s0 + wr0 + l15) * HID_ + h * D_;
    float vals[4][8];
    float ss = 0.0f;
    for (int kc = 0; kc < 4; kc++) {
      uint4 u = *(const uint4*)&qr[kc * 32 + quad * 8];
      u32 uu[4] = {u.x, u.y, u.z, u.w};
      for (int e = 0; e < 4; e++) {
        float lo = bf2f(uu[e] & 0xffff), hi = bf2f(uu[e] >> 16);
        vals[kc][2 * e] = lo;
        vals[kc][2 * e + 1] = hi;
        ss += lo * lo + hi * hi;
      }
    }
    ss += __shfl_xor(ss, 16);
    ss += __shfl_xor(ss, 32);
    float scale = rsqrtf(ss * (1.0f / 128.0f) + EPS_) * cexp;
    for (int kc = 0; kc < 4; kc++) {
      float4 w0 = *(const float4*)&nw[kc * 32 + quad * 8];
      float4 w1 = *(const float4*)&nw[kc * 32 + quad * 8 + 4];
      union { u32x4v u; bf16x8 v; } q;
      q.u.x = pack_bf16(vals[kc][0] * scale * w0.x, vals[kc][1] * scale * w0.y);
      q.u.y = pack_bf16(vals[kc][2] * scale * w0.z, vals[kc][3] * scale * w0.w);
      q.u.z = pack_bf16(vals[kc][4] * scale * w1.x, vals[kc][5] * scale * w1.y);
      q.u.w = pack_bf16(vals[kc][6] * scale * w1.z, vals[kc][7] * scale * w1.w);
      qf[kc] = q.v;
    }
  }

  float psum = 0.0f;
  f32x4 o[8];
  for (int n = 0; n < 8; n++)
    for (int r = 0; r < 4; r++) o[n][r] = 0.0f;

  stage(0, 0);
  int cur = 0;
  const int NT = L_ / 64;  // 32
  for (int t = 0; t < NT; t++) {
    if (t + 1 < NT) {
      stage((t + 1) * 64, cur ^ 1);
      // tile t's 4 oldest loads (per wave) must land; t+1's 4 stay in flight.
      asm volatile("s_waitcnt vmcnt(4)\n\ts_barrier" ::: "memory");
    } else {
      asm volatile("s_waitcnt vmcnt(0)\n\ts_barrier" ::: "memory");
    }

    // this wave: q-rows [wr0, wr0+16), l-half lh of the 64-l tile
    {
      f32x4 sacc[2];
      for (int jj = 0; jj < 2; jj++)
        for (int r = 0; r < 4; r++) sacc[jj][r] = 0.0f;
      __builtin_amdgcn_s_setprio(1);
      for (int jj = 0; jj < 2; jj++) {
        int j = lh * 2 + jj;
        for (int kc = 0; kc < 4; kc++) {
          bf16x8 kf = *(const bf16x8*)&sm.s.sk[cur][kc][(j * 16 + l15) * 32 + swq];
          sacc[jj] = __builtin_amdgcn_mfma_f32_16x16x32_bf16(kf, qf[kc], sacc[jj], 0, 0, 0);
        }
      }
      __builtin_amdgcn_s_setprio(0);
      // p = exp2(s); per-lane partial row sums; pack + C->A in registers
      union { u32x4v u; bf16x8 v; } pf;
      {
        float p0[4], p1[4];
        for (int r = 0; r < 4; r++) {
          p0[r] = fexp2(sacc[0][r]);
          p1[r] = fexp2(sacc[1][r]);
          psum += p0[r] + p1[r];
        }
        u32 xa = pack_bf16(p0[0], p0[1]), xb = pack_bf16(p0[2], p0[3]);
        u32 ya = pack_bf16(p1[0], p1[1]), yb = pack_bf16(p1[2], p1[3]);
        pf.u = ctoa(xa, xb, ya, yb, quad, l15);
      }
      // O += P V for this wave's 32-l half
      __builtin_amdgcn_s_setprio(1);
      for (int n = 0; n < 8; n++) {
        bf16x8 vf = *(const bf16x8*)&sm.s.sv[cur][lh][(n * 16 + l15) * 32 + swq];
        o[n] = __builtin_amdgcn_mfma_f32_16x16x32_bf16(pf.v, vf, o[n], 0, 0, 0);
      }
      __builtin_amdgcn_s_setprio(0);
    }
    // all waves done reading buf[cur] before it is restaged next iteration
    asm volatile("s_barrier" ::: "memory");
    cur ^= 1;
  }

  // ---- epilogue: cross-wave (lh) reduce of O and psum, then scale+store ----
  // quad-reduce psum: value valid for q-row = l15, replicated per quad
  float sred = psum;
  sred += __shfl_xor(sred, 16);
  sred += __shfl_xor(sred, 32);
  if (lh == 1) {
    for (int n = 0; n < 8; n++)
      for (int r = 0; r < 4; r++)
        sm.e.ob[qsub][quad * 4 + r][n * 16 + l15] = o[n][r];
    if (quad == 0) sm.e.ps[qsub][l15] = sred;
  }
  __syncthreads();
  if (lh == 0) {
    float stot = sred + sm.e.ps[qsub][l15];
    float linv = 1.0f / stot;
    float lr[4];
    for (int r = 0; r < 4; r++) lr[r] = __shfl(linv, quad * 4 + r);
    u16* ob = AO + (size_t)(b * S_ + s0 + wr0) * HID_ + h * D_;
    for (int n = 0; n < 8; n++)
      for (int r = 0; r < 4; r++) {
        float v = o[n][r] + sm.e.ob[qsub][quad * 4 + r][n * 16 + l15];
        ob[(size_t)(quad * 4 + r) * HID_ + n * 16 + l15] = f2bf(v * lr[r]);
      }
  }
}

// ---------------- launch ----------------
extern "C" void kernel_launch(void* const* d_in, const int* in_sizes, int n_in,
                              void* d_out, int out_size, void* d_ws, size_t ws_size,
                              hipStream_t stream) {
  const float* x = (const float*)d_in[0];
  const float* c = (const float*)d_in[1];
  const float* wq = (const float*)d_in[2];
  const float* wkv = (const float*)d_in[3];
  const float* wo = (const float*)d_in[4];
  const float* nqw = (const float*)d_in[5];
  const float* nkw = (const float*)d_in[6];
  float* out = (float*)d_out;

  const int M = B_ * S_;  // 4096
  char* p = (char*)d_ws;
  auto alloc = [&](size_t bytes) {
    char* r = p;
    p += (bytes + 255) & ~(size_t)255;
    return r;
  };
  u16* xbf = (u16*)alloc((size_t)M * HID_ * 2);
  u16* cbf = (u16*)alloc((size_t)M * HID_ * 2);
  u16* wqT = (u16*)alloc((size_t)HID_ * HID_ * 2);
  u16* wkvT = (u16*)alloc((size_t)1024 * HID_ * 2);
  u16* woT = (u16*)alloc((size_t)HID_ * HID_ * 2);
  u16* XQ = (u16*)alloc((size_t)M * HID_ * 2);
  u16* CKV = (u16*)alloc((size_t)M * 1024 * 2);
  u16* Kb = (u16*)alloc((size_t)B_ * KVH_ * L_ * D_ * 2);
  u16* Vt = (u16*)alloc((size_t)B_ * KVH_ * D_ * L_ * 2);
  u16* AO = (u16*)alloc((size_t)M * HID_ * 2);

  cvt_bf16<<<8192, 256, 0, stream>>>(x, xbf, M * HID_ / 4);
  cvt_bf16<<<8192, 256, 0, stream>>>(c, cbf, M * HID_ / 4);
  transp_bf16<<<dim3(32, 32), 256, 0, stream>>>(wq, wqT, HID_, HID_);
  transp_bf16<<<dim3(16, 32), 256, 0, stream>>>(wkv, wkvT, HID_, 1024);
  transp_bf16<<<dim3(32, 32), 256, 0, stream>>>(wo, woT, HID_, HID_);
  gemm_bt<u16><<<dim3(32, 16), 256, 0, stream>>>(xbf, wqT, XQ, M, HID_, HID_);
  gemm_bt<u16><<<dim3(32, 8), 256, 0, stream>>>(cbf, wkvT, CKV, M, 1024, HID_);
  knorm_deint<<<dim3(32, 4, 2), 256, 0, stream>>>(CKV, nkw, Kb, Vt);
  attn<<<dim3(32, 16, 2), 512, 0, stream>>>(XQ, nqw, Kb, Vt, AO);
  gemm_bt<float><<<dim3(32, 16), 256, 0, stream>>>(AO, woT, out, M, HID_, HID_);
}

// Round 6
// 361.076 us; speedup vs baseline: 1.4476x; 1.1172x over previous
//
#include <hip/hip_runtime.h>

#define B_ 2
#define S_ 2048
#define L_ 2048
#define H_ 16
#define KVH_ 4
#define D_ 128
#define HID_ 2048
#define EPS_ 1e-6f

typedef unsigned short u16;
typedef unsigned int u32;
typedef __bf16 bf16x8 __attribute__((ext_vector_type(8)));
typedef float f32x4 __attribute__((ext_vector_type(4)));
typedef unsigned u32x2v __attribute__((ext_vector_type(2)));
typedef unsigned u32x4v __attribute__((ext_vector_type(4)));

__device__ __forceinline__ float bf2f(u32 u) {
  union { u32 i; float f; } x; x.i = u << 16; return x.f;
}
__device__ __forceinline__ u16 f2bf(float f) {
  union { float f; u32 i; } x; x.f = f;
  return (u16)((x.i + 0x7fffu + ((x.i >> 16) & 1u)) >> 16);
}
__device__ __forceinline__ u32 pack_bf16(float a, float b) {
#if __has_builtin(__builtin_amdgcn_cvt_pk_bf16_f32)
  typedef __bf16 bf16x2 __attribute__((ext_vector_type(2)));
  union { bf16x2 v; u32 u; } c;
  c.v = __builtin_amdgcn_cvt_pk_bf16_f32(a, b);
  return c.u;
#else
  return (u32)f2bf(a) | ((u32)f2bf(b) << 16);
#endif
}
__device__ __forceinline__ float fexp2(float x) {
#if __has_builtin(__builtin_amdgcn_exp2f)
  return __builtin_amdgcn_exp2f(x);  // single v_exp_f32; softmax tolerates FTZ
#else
  return exp2f(x);
#endif
}
// async global->LDS, 16B per lane. LDS dest = wave-uniform base + lane*16.
__device__ __forceinline__ void gl2lds16(const u16* g, u16* l) {
  __builtin_amdgcn_global_load_lds(
      (const __attribute__((address_space(1))) u32*)g,
      (__attribute__((address_space(3))) u32*)l, 16, 0, 0);
}

#if __has_builtin(__builtin_amdgcn_permlane32_swap) && __has_builtin(__builtin_amdgcn_permlane16_swap)
#define HAS_PLS 1
#else
#define HAS_PLS 0
#endif

// MFMA C-layout (2 16x16 tiles, packed bf16 pairs) -> one K=32 A-frag.
__device__ __forceinline__ u32x4v ctoa(u32 xa, u32 xb, u32 ya, u32 yb,
                                       int quad, int l15) {
  u32x4v f;
#if HAS_PLS
  u32x2v t1 = __builtin_amdgcn_permlane32_swap(xa, ya, false, false);
  u32x2v t2 = __builtin_amdgcn_permlane16_swap(t1.x, t1.y, false, false);
  u32x2v t3 = __builtin_amdgcn_permlane32_swap(xb, yb, false, false);
  u32x2v t4 = __builtin_amdgcn_permlane16_swap(t3.x, t3.y, false, false);
  f.x = t2.x; f.y = t4.x; f.z = t2.y; f.w = t4.y;
#else
  int a0 = (((2 * quad) & 3) * 16 + l15) << 2;
  int a1 = (((2 * quad + 1) & 3) * 16 + l15) << 2;
  u32 xa0 = __builtin_amdgcn_ds_bpermute(a0, xa), ya0 = __builtin_amdgcn_ds_bpermute(a0, ya);
  u32 xb0 = __builtin_amdgcn_ds_bpermute(a0, xb), yb0 = __builtin_amdgcn_ds_bpermute(a0, yb);
  u32 xa1 = __builtin_amdgcn_ds_bpermute(a1, xa), ya1 = __builtin_amdgcn_ds_bpermute(a1, ya);
  u32 xb1 = __builtin_amdgcn_ds_bpermute(a1, xb), yb1 = __builtin_amdgcn_ds_bpermute(a1, yb);
  bool hi = quad >= 2;
  f.x = hi ? ya0 : xa0; f.y = hi ? yb0 : xb0;
  f.z = hi ? ya1 : xa1; f.w = hi ? yb1 : xb1;
#endif
  return f;
}

// ---------------- elementwise fp32 -> bf16 cast ----------------
__global__ __launch_bounds__(256) void cvt_bf16(const float* __restrict__ in,
                                                u16* __restrict__ out, int n4) {
  int i = blockIdx.x * 256 + threadIdx.x;
  if (i >= n4) return;
  float4 v = ((const float4*)in)[i];
  uint2 o;
  o.x = pack_bf16(v.x, v.y);
  o.y = pack_bf16(v.z, v.w);
  ((uint2*)out)[i] = o;
}

// ---------------- LDS-tiled transpose fp32[R][C] -> bf16[C][R] ----------------
__global__ __launch_bounds__(256) void transp_bf16(const float* __restrict__ A,
                                                   u16* __restrict__ At, int R, int C) {
  __shared__ float t[64][65];
  int c0 = blockIdx.x * 64, r0 = blockIdx.y * 64;
  int tx = threadIdx.x & 63, ty = threadIdx.x >> 6;
  for (int i = ty; i < 64; i += 4)
    t[i][tx] = A[(size_t)(r0 + i) * C + c0 + tx];
  __syncthreads();
  for (int i = ty; i < 64; i += 4)
    At[(size_t)(c0 + i) * R + r0 + tx] = f2bf(t[tx][i]);
}

// ---------------- bf16 GEMM: C[M][N] = A[M][K] @ Bt[N][K]^T ----------------
// BK=64 (half the barriers of BK=32) + XOR-swizzled LDS tiles: at 128B rows a
// linear layout is a 16-way read conflict; slot ^= (row&7) on BOTH the staged
// global source and the ds_read makes reads 2-way (free). LDS 32KB, 2 blk/CU.
__device__ __forceinline__ void store_out(u16* p, float v) { *p = f2bf(v); }
__device__ __forceinline__ void store_out(float* p, float v) { *p = v; }

template <typename OutT>
__global__ __launch_bounds__(256, 2) void gemm_bt(const u16* __restrict__ A,
                                                  const u16* __restrict__ Bt,
                                                  OutT* __restrict__ C,
                                                  int M, int N, int K) {
  __shared__ u16 sA[128 * 64];
  __shared__ u16 sB[128 * 64];
  const int tid = threadIdx.x;
  const int wave = tid >> 6, lane = tid & 63;
  const int quad = lane >> 4, l15 = lane & 15;
  const int m0 = blockIdx.x * 128, n0 = blockIdx.y * 128;
  const int wm = (wave >> 1) * 64, wn = (wave & 1) * 64;
  const u16* aP = A + (size_t)m0 * K;
  const u16* bP = Bt + (size_t)n0 * K;
  // staging: dest row = base + lane>>3, dest 16B-slot = lane&7 (linear);
  // source slot = (lane&7) ^ ((lane>>3)&7)  => LDS[r][s] = g[r][s ^ (r&7)]
  const int sr = lane >> 3;
  const int sc = ((lane & 7) ^ ((lane >> 3) & 7)) * 8;
  const int r0 = wave * 32;
  const int sw = l15 & 7;  // read-side XOR key (row&7 == l15&7)

  f32x4 acc[4][4];
  for (int i = 0; i < 4; i++)
    for (int j = 0; j < 4; j++)
      for (int r = 0; r < 4; r++) acc[i][j][r] = 0.0f;

  for (int k0 = 0; k0 < K; k0 += 64) {
    for (int is = 0; is < 4; is++) {
      gl2lds16(aP + (size_t)(r0 + is * 8 + sr) * K + k0 + sc, &sA[(r0 + is * 8) * 64]);
      gl2lds16(bP + (size_t)(r0 + is * 8 + sr) * K + k0 + sc, &sB[(r0 + is * 8) * 64]);
    }
    __syncthreads();
    for (int ks = 0; ks < 2; ks++) {
      bf16x8 afrag[4], bfrag[4];
      for (int i = 0; i < 4; i++)
        afrag[i] = *(const bf16x8*)&sA[(wm + i * 16 + l15) * 64 + ((ks * 4 + quad) ^ sw) * 8];
      for (int j = 0; j < 4; j++)
        bfrag[j] = *(const bf16x8*)&sB[(wn + j * 16 + l15) * 64 + ((ks * 4 + quad) ^ sw) * 8];
      for (int i = 0; i < 4; i++)
        for (int j = 0; j < 4; j++)
          acc[i][j] = __builtin_amdgcn_mfma_f32_16x16x32_bf16(afrag[i], bfrag[j], acc[i][j], 0, 0, 0);
    }
    __syncthreads();
  }
  for (int i = 0; i < 4; i++)
    for (int j = 0; j < 4; j++) {
      int row = m0 + wm + i * 16 + quad * 4;
      int col = n0 + wn + j * 16 + l15;
      for (int r = 0; r < 4; r++)
        store_out(&C[(size_t)(row + r) * N + col], acc[i][j][r]);
    }
}

// ---------------- K-norm + deinterleave CKV -> K, V^T (coalesced) ----------------
__global__ __launch_bounds__(256) void knorm_deint(const u16* __restrict__ CKV,
                                                   const float* __restrict__ w,
                                                   u16* __restrict__ K,
                                                   u16* __restrict__ Vt) {
  __shared__ u16 vbuf[128][66];
  const int tid = threadIdx.x, wave = tid >> 6, lane = tid & 63;
  const int l0 = blockIdx.x * 64, kvh = blockIdx.y, b = blockIdx.z;
  for (int it = 0; it < 16; it++) {
    int ll = wave * 16 + it;
    int row = b * L_ + l0 + ll;
    const u16* src = CKV + (size_t)row * 1024 + kvh * 256;
    u32 p0 = *(const u32*)&src[lane * 2];
    u32 p1 = *(const u32*)&src[(lane + 64) * 2];
    float k0 = bf2f(p0 & 0xffff), v0 = bf2f(p0 >> 16);
    float k1 = bf2f(p1 & 0xffff), v1 = bf2f(p1 >> 16);
    float ss = k0 * k0 + k1 * k1;
    for (int off = 1; off < 64; off <<= 1) ss += __shfl_xor(ss, off);
    float sc = rsqrtf(ss * (1.0f / 128.0f) + EPS_);
    size_t kb = (((size_t)b * KVH_ + kvh) * L_ + l0 + ll) * D_;
    K[kb + lane] = f2bf(k0 * sc * w[lane]);
    K[kb + lane + 64] = f2bf(k1 * sc * w[lane + 64]);
    vbuf[lane][ll] = f2bf(v0);
    vbuf[lane + 64][ll] = f2bf(v1);
  }
  __syncthreads();
  for (int it = tid; it < 128 * 32; it += 256) {
    int d = it >> 5, cc = (it & 31) * 2;
    u32 pk = (u32)vbuf[d][cc] | ((u32)vbuf[d][cc + 1] << 16);
    *(u32*)&Vt[(((size_t)b * KVH_ + kvh) * D_ + d) * L_ + l0 + cc] = pk;
  }
}

// ---------------- flash attention (exact R3: best measured 86.7us) ----------------
// 8 waves x 16 q-rows (512-thread block): 2 blocks/CU, 4 waves/SIMD.
// KV-tile 64 double-buffered, counted-vmcnt raw barriers (tile t+1's 4
// loads/wave in flight across the barrier), LDS XOR-swizzle, setprio.
// This structure runs at ~92% of the ds_read_b128 throughput ceiling
// (reuse-1: 1KB LDS per MFMA) -- its structural floor is ~80us.
__global__ __launch_bounds__(512, 4) void attn(const u16* __restrict__ XQ,
                                               const float* __restrict__ nw,
                                               const u16* __restrict__ K,
                                               const u16* __restrict__ Vt,
                                               u16* __restrict__ AO) {
  __shared__ u16 sk[2][4][64 * 32];   // [buf][d-chunk][l-row 64][32 d]  32KB
  __shared__ u16 sv[2][2][128 * 32];  // [buf][l-chunk][d-row 128][32 l] 32KB
  const int tid = threadIdx.x, wave = tid >> 6, lane = tid & 63;
  const int quad = lane >> 4, l15 = lane & 15;
  const int qt = blockIdx.x, h = blockIdx.y, b = blockIdx.z;
  const int kvh = h >> 2;
  const int s0 = qt * 128, wr0 = wave * 16;

  const u16* kbase = K + ((size_t)(b * KVH_ + kvh) * L_) * D_;
  const u16* vbase = Vt + ((size_t)(b * KVH_ + kvh) * D_) * L_;
  const int srow = lane >> 2;
  const int scol = ((lane & 3) ^ ((lane >> 3) & 3)) * 8;
  const int swq = (quad ^ ((l15 >> 1) & 3)) * 8;  // read-side XOR
  const int kch = wave >> 1, khalf = wave & 1;   // K: d-chunk, row-half
  const int vch = wave >> 2, vqtr = wave & 3;    // V: l-chunk, d-quarter

  auto stage = [&](int l0, int buf) {
    const u16* kb = kbase + (size_t)l0 * D_ + kch * 32;
    for (int is = 0; is < 2; is++) {
      int row = khalf * 32 + is * 16;
      gl2lds16(kb + (size_t)(row + srow) * D_ + scol, &sk[buf][kch][row * 32]);
    }
    const u16* vb = vbase + l0 + vch * 32;
    for (int is = 0; is < 2; is++) {
      int drow = vqtr * 32 + is * 16;
      gl2lds16(vb + (size_t)(drow + srow) * L_ + scol, &sv[buf][vch][drow * 32]);
    }
  };

  // ---- one-time: load 16 q-rows, fused RMSNorm (+SCALE*log2e), to A-frags ----
  bf16x8 qf[4];
  {
    const float cexp = 0.12753102331322172f;  // (1/sqrt(128)) * log2(e)
    const u16* qr = XQ + (size_t)(b * S_ + s0 + wr0 + l15) * HID_ + h * D_;
    float vals[4][8];
    float ss = 0.0f;
    for (int kc = 0; kc < 4; kc++) {
      uint4 u = *(const uint4*)&qr[kc * 32 + quad * 8];
      u32 uu[4] = {u.x, u.y, u.z, u.w};
      for (int e = 0; e < 4; e++) {
        float lo = bf2f(uu[e] & 0xffff), hi = bf2f(uu[e] >> 16);
        vals[kc][2 * e] = lo;
        vals[kc][2 * e + 1] = hi;
        ss += lo * lo + hi * hi;
      }
    }
    ss += __shfl_xor(ss, 16);
    ss += __shfl_xor(ss, 32);
    float scale = rsqrtf(ss * (1.0f / 128.0f) + EPS_) * cexp;
    for (int kc = 0; kc < 4; kc++) {
      float4 w0 = *(const float4*)&nw[kc * 32 + quad * 8];
      float4 w1 = *(const float4*)&nw[kc * 32 + quad * 8 + 4];
      union { u32x4v u; bf16x8 v; } q;
      q.u.x = pack_bf16(vals[kc][0] * scale * w0.x, vals[kc][1] * scale * w0.y);
      q.u.y = pack_bf16(vals[kc][2] * scale * w0.z, vals[kc][3] * scale * w0.w);
      q.u.z = pack_bf16(vals[kc][4] * scale * w1.x, vals[kc][5] * scale * w1.y);
      q.u.w = pack_bf16(vals[kc][6] * scale * w1.z, vals[kc][7] * scale * w1.w);
      qf[kc] = q.v;
    }
  }

  float psum = 0.0f;
  f32x4 o[8];
  for (int n = 0; n < 8; n++)
    for (int r = 0; r < 4; r++) o[n][r] = 0.0f;

  stage(0, 0);
  int cur = 0;
  const int NT = L_ / 64;  // 32
  for (int t = 0; t < NT; t++) {
    if (t + 1 < NT) {
      stage((t + 1) * 64, cur ^ 1);
      asm volatile("s_waitcnt vmcnt(4)\n\ts_barrier" ::: "memory");
    } else {
      asm volatile("s_waitcnt vmcnt(0)\n\ts_barrier" ::: "memory");
    }

    for (int cc = 0; cc < 2; cc++) {
      f32x4 sacc[2];
      for (int jj = 0; jj < 2; jj++)
        for (int r = 0; r < 4; r++) sacc[jj][r] = 0.0f;
      __builtin_amdgcn_s_setprio(1);
      for (int jj = 0; jj < 2; jj++) {
        int j = cc * 2 + jj;
        for (int kc = 0; kc < 4; kc++) {
          bf16x8 kf = *(const bf16x8*)&sk[cur][kc][(j * 16 + l15) * 32 + swq];
          sacc[jj] = __builtin_amdgcn_mfma_f32_16x16x32_bf16(kf, qf[kc], sacc[jj], 0, 0, 0);
        }
      }
      __builtin_amdgcn_s_setprio(0);
      union { u32x4v u; bf16x8 v; } pf;
      {
        float p0[4], p1[4];
        for (int r = 0; r < 4; r++) {
          p0[r] = fexp2(sacc[0][r]);
          p1[r] = fexp2(sacc[1][r]);
          psum += p0[r] + p1[r];
        }
        u32 xa = pack_bf16(p0[0], p0[1]), xb = pack_bf16(p0[2], p0[3]);
        u32 ya = pack_bf16(p1[0], p1[1]), yb = pack_bf16(p1[2], p1[3]);
        pf.u = ctoa(xa, xb, ya, yb, quad, l15);
      }
      __builtin_amdgcn_s_setprio(1);
      for (int n = 0; n < 8; n++) {
        bf16x8 vf = *(const bf16x8*)&sv[cur][cc][(n * 16 + l15) * 32 + swq];
        o[n] = __builtin_amdgcn_mfma_f32_16x16x32_bf16(pf.v, vf, o[n], 0, 0, 0);
      }
      __builtin_amdgcn_s_setprio(0);
    }
    asm volatile("s_barrier" ::: "memory");
    cur ^= 1;
  }

  // epilogue: reduce psum across quads (lane=q replicated), scale, store
  {
    float s = psum;
    s += __shfl_xor(s, 16);
    s += __shfl_xor(s, 32);
    float linv = 1.0f / s;
    float lr[4];
    for (int r = 0; r < 4; r++) lr[r] = __shfl(linv, quad * 4 + r);
    u16* ob = AO + (size_t)(b * S_ + s0 + wr0) * HID_ + h * D_;
    for (int n = 0; n < 8; n++)
      for (int r = 0; r < 4; r++)
        ob[(size_t)(quad * 4 + r) * HID_ + n * 16 + l15] = f2bf(o[n][r] * lr[r]);
  }
}

// ---------------- launch ----------------
extern "C" void kernel_launch(void* const* d_in, const int* in_sizes, int n_in,
                              void* d_out, int out_size, void* d_ws, size_t ws_size,
                              hipStream_t stream) {
  const float* x = (const float*)d_in[0];
  const float* c = (const float*)d_in[1];
  const float* wq = (const float*)d_in[2];
  const float* wkv = (const float*)d_in[3];
  const float* wo = (const float*)d_in[4];
  const float* nqw = (const float*)d_in[5];
  const float* nkw = (const float*)d_in[6];
  float* out = (float*)d_out;

  const int M = B_ * S_;  // 4096
  char* p = (char*)d_ws;
  auto alloc = [&](size_t bytes) {
    char* r = p;
    p += (bytes + 255) & ~(size_t)255;
    return r;
  };
  u16* xbf = (u16*)alloc((size_t)M * HID_ * 2);
  u16* cbf = (u16*)alloc((size_t)M * HID_ * 2);
  u16* wqT = (u16*)alloc((size_t)HID_ * HID_ * 2);
  u16* wkvT = (u16*)alloc((size_t)1024 * HID_ * 2);
  u16* woT = (u16*)alloc((size_t)HID_ * HID_ * 2);
  u16* XQ = (u16*)alloc((size_t)M * HID_ * 2);
  u16* CKV = (u16*)alloc((size_t)M * 1024 * 2);
  u16* Kb = (u16*)alloc((size_t)B_ * KVH_ * L_ * D_ * 2);
  u16* Vt = (u16*)alloc((size_t)B_ * KVH_ * D_ * L_ * 2);
  u16* AO = (u16*)alloc((size_t)M * HID_ * 2);

  cvt_bf16<<<8192, 256, 0, stream>>>(x, xbf, M * HID_ / 4);
  cvt_bf16<<<8192, 256, 0, stream>>>(c, cbf, M * HID_ / 4);
  transp_bf16<<<dim3(32, 32), 256, 0, stream>>>(wq, wqT, HID_, HID_);
  transp_bf16<<<dim3(16, 32), 256, 0, stream>>>(wkv, wkvT, HID_, 1024);
  transp_bf16<<<dim3(32, 32), 256, 0, stream>>>(wo, woT, HID_, HID_);
  gemm_bt<u16><<<dim3(32, 16), 256, 0, stream>>>(xbf, wqT, XQ, M, HID_, HID_);
  gemm_bt<u16><<<dim3(32, 8), 256, 0, stream>>>(cbf, wkvT, CKV, M, 1024, HID_);
  knorm_deint<<<dim3(32, 4, 2), 256, 0, stream>>>(CKV, nkw, Kb, Vt);
  attn<<<dim3(16, 16, 2), 512, 0, stream>>>(XQ, nqw, Kb, Vt, AO);
  gemm_bt<float><<<dim3(32, 16), 256, 0, stream>>>(AO, woT, out, M, HID_, HID_);
}